// Round 17
// baseline (71.978 us; speedup 1.0000x reference)
//
#include <hip/hip_runtime.h>
#include <hip/hip_bf16.h>

// T=6, B=2, Q=50 -> P=100 queries; N=8 targets; 72x72 -> 288x288 bilinear
// (align_corners=False, 4x => fixed weights); out C[B,Q,N] = 800 f32.
// R17 = R16 with the staging yloc fix: job/16 is a SHIFT (job>>4), the magic
// 2731 computed job/24 and left rows 4-5 unstaged (NaN). 512-thr blocks,
// shared 6-row pred stage, 39.7KB LDS -> 4 blocks/CU.

#define T_      6
#define P_      100
#define N_      8
#define HIN     72
#define SIN     (HIN*HIN)        // 5184
#define HOUT    288
#define S_OUT   (HOUT*HOUT)      // 82944
#define NQG     7                // query groups of 16 (100 -> 112 padded)
#define NCH     18               // 16-output-row slabs per t
#define PART_F  320              // floats per partial slot
#define WS2_OFF (T_*NQG*NCH*PART_F)          // 241920
#define NQUAD   (S_OUT/4)        // 20736 float4 per mask
#define NLOG2E  (-1.4426950408889634f)

// LDS map (bytes):
//  pred u32(L|S) [yloc6][q16][colidx74]  colidx = realcol+1
//    strides: col 4, q 296, yloc 4736 ; total 28416
//  g tiles [wave8][1280] : 28416 .. 38656
//  iredN [8][16] f32 : 38656 ; iredD : 39168 ; total 39680
//  cred [8][64][8] f32 (16KB) aliases pred area post-loop
#define Q_STR   296
#define Y_STR   4736
#define LDS_G   28416
#define GW      1280
#define LDS_IRN (LDS_G + 8*GW)        // 38656
#define LDS_IRD (LDS_IRN + 512)       // 39168
#define LDS_TOT (LDS_IRD + 512)       // 39680

typedef __attribute__((ext_vector_type(8))) short short8;
typedef __attribute__((ext_vector_type(4))) float f32x4;
typedef __attribute__((ext_vector_type(2))) float f32x2;

__device__ __forceinline__ unsigned cvt_pk_bf16(float lo, float hi) {
    unsigned r;
    asm("v_cvt_pk_bf16_f32 %0, %1, %2" : "=v"(r) : "v"(lo), "v"(hi));
    return r;
}
__device__ __forceinline__ f32x2 pk_mul(f32x2 a, f32x2 b) {
    f32x2 d;
    asm("v_pk_mul_f32 %0, %1, %2" : "=v"(d) : "v"(a), "v"(b));
    return d;
}
__device__ __forceinline__ f32x2 pk_fma(f32x2 a, f32x2 b, f32x2 c) {
    f32x2 d;
    asm("v_pk_fma_f32 %0, %1, %2, %3" : "=v"(d) : "v"(a), "v"(b), "v"(c));
    return d;
}
__device__ __forceinline__ float blo(unsigned r) { return __uint_as_float(r << 16); }
__device__ __forceinline__ float bhi(unsigned r) { return __uint_as_float(r & 0xffff0000u); }

// a = sigmoid(u) where m = -log2e*u  =>  a = 1/(1+2^m)   (packed L,S)
__device__ __forceinline__ f32x2 sigm2m(f32x2 m) {
    f32x2 e;
    e.x = __builtin_amdgcn_exp2f(m.x);
    e.y = __builtin_amdgcn_exp2f(m.y);
    f32x2 d = e + 1.0f;
    f32x2 r;
    r.x = __builtin_amdgcn_rcpf(d.x);
    r.y = __builtin_amdgcn_rcpf(d.y);
    return r;
}

// ---------------------------------------------------------------------------
// Kernel 1: staged-LDS packed act + MFMA. grid = T_*NQG*NCH, 512 thr (8 waves).
// ---------------------------------------------------------------------------
__global__ __launch_bounds__(512, 8) void mfma_partial(
    const float* __restrict__ predL, const float* __restrict__ predS,
    const float* __restrict__ tgt, float* __restrict__ ws)
{
    __shared__ __align__(16) char smem[LDS_TOT];
    float (*cred)[64][8] = (float (*)[64][8])smem;   // aliases pred area (post-loop)
    float* iredN = (float*)(smem + LDS_IRN);
    float* iredD = (float*)(smem + LDS_IRD);

    const int blk = blockIdx.x;                 // (t*NQG+qg)*NCH + ch
    const int t   = blk / (NQG*NCH);
    const int rem = blk % (NQG*NCH);
    const int qg  = rem / NCH;
    const int ch  = rem % NCH;

    const int lane = threadIdx.x & 63;
    const int wv   = threadIdx.x >> 6;          // 0..7
    char* gpl = smem + LDS_G + wv*GW;

    const int arow = lane & 15;                 // q row (A) / B-col select
    const int kg   = lane >> 4;                 // k-group
    const int arowc = (arow < 9) ? arow : 9;    // g-tile row (9 = shared zeros)

    const float* __restrict__ pLt = predL + (size_t)t*P_*SIN;
    const float* __restrict__ pSt = predS + (size_t)t*P_*SIN;

    // --- one-time staging: 6 input rows x 16 q, interleaved bf16 (L|S) ---
    {
        const int tid = threadIdx.x;
#pragma unroll
        for (int pass = 0; pass < 4; ++pass) {
            const int idx = pass*512 + tid;
            if (idx < 1728) {                          // 96 jobs x 18 float4
                const int job = (idx*3641) >> 16;      // idx / 18
                const int f4i = idx - job*18;
                const int yloc = job >> 4;             // job / 16 (0..5)  [R17 fix]
                const int ql = job & 15;
                const int qv = min(qg*16 + ql, P_-1);
                const int grow = min(max(4*ch - 1 + yloc, 0), HIN-1);
                const size_t so = (size_t)qv*SIN + grow*HIN + 4*f4i;
                const float4 vL = *(const float4*)(pLt + so);
                const float4 vS = *(const float4*)(pSt + so);
                char* dp = smem + yloc*Y_STR + ql*Q_STR + 4 + 16*f4i;
                *(unsigned*)(dp)    = cvt_pk_bf16(vL.x, vS.x);
                *(unsigned*)(dp+4)  = cvt_pk_bf16(vL.y, vS.y);
                *(unsigned*)(dp+8)  = cvt_pk_bf16(vL.z, vS.z);
                *(unsigned*)(dp+12) = cvt_pk_bf16(vL.w, vS.w);
            }
        }
        if (tid < 192) {   // clamp cols: colidx 0 (real -1) and 73 (real 72)
            const int job = tid >> 1, edge = tid & 1;
            const int yloc = job >> 4;                 // [R17 fix]
            const int ql = job & 15;
            const int qv = min(qg*16 + ql, P_-1);
            const int grow = min(max(4*ch - 1 + yloc, 0), HIN-1);
            const size_t so = (size_t)qv*SIN + grow*HIN + (edge ? HIN-1 : 0);
            *(unsigned*)(smem + yloc*Y_STR + ql*Q_STR + (edge ? 292 : 0))
                = cvt_pk_bf16(pLt[so], pSt[so]);
        }
    }

    // g-stage roles (validated): n = lane>>3, f = lane&7
    const int gn = lane >> 3, gf = lane & 7;
    const float4* __restrict__ tgt4 = (const float4*)tgt + (size_t)t*8*NQUAD;
    const int gq0 = gn*NQUAD + gf;
    const int gwoff = (gn*128 + 8*gf) ^ ((gn&7)<<4);
    if (lane < 16) {   // row 8 = ones column; row 9 = shared zero row
        *(uint2*)(gpl + 1024 + 8*lane) = make_uint2(0x3F803F80u, 0x3F803F80u);
        *(uint2*)(gpl + 1152 + 8*lane) = make_uint2(0u, 0u);
    }

    __syncthreads();   // staged pred visible to all waves

    short8 ones8;
#pragma unroll
    for (int j8 = 0; j8 < 8; j8++) ones8[j8] = (short)0x3F80;
    const bool padQ = (qg == NQG-1) && (arow >= 4);

    const f32x2 c375 = {0.375f, 0.375f}, c625 = {0.625f, 0.625f};
    const f32x2 c125 = {0.125f, 0.125f}, c875 = {0.875f, 0.875f};

    f32x4 accL = {0.f,0.f,0.f,0.f}, accS = {0.f,0.f,0.f,0.f};
    f32x2 iN2 = {0.f,0.f}, iD2 = {0.f,0.f};
    const int qb = arow*Q_STR;

    // --- g software pipeline: prefetch iter 0 ---
    float4 ga, gb;
    {
        const int f4b = (ch*4608 + wv*64) >> 2;
        ga = tgt4[gq0 + f4b];
        gb = tgt4[gq0 + f4b + 8];
    }

    for (int it = 0; it < 9; ++it) {
        const int px0 = ch*4608 + it*512 + wv*64;

        // --- stage current g chunk from regs (bf16, swizzled [n][k]) ---
        {
            uint2 pa, pb;
            pa.x = cvt_pk_bf16(ga.x, ga.y); pa.y = cvt_pk_bf16(ga.z, ga.w);
            pb.x = cvt_pk_bf16(gb.x, gb.y); pb.y = cvt_pk_bf16(gb.z, gb.w);
            *(uint2*)(gpl + gwoff) = pa;
            *(uint2*)(gpl + (gwoff ^ 64)) = pb;   // base bit6==0 pre-swz
        }
        // --- prefetch next iter's g: latency hides under the act stretch ---
        if (it < 8) {
            const int f4b = (px0 + 512) >> 2;
            ga = tgt4[gq0 + f4b];
            gb = tgt4[gq0 + f4b + 8];
        }

#pragma unroll
        for (int ks = 0; ks < 2; ++ks) {
            const unsigned pp = px0 + 32*ks + 8*kg;   // lane's 8-px start
            const unsigned row = pp / 288u;
            const int ry = row & 3, j = row >> 2;
            const int y0loc = (j - 4*ch) + (ry >> 1);        // slab-local top row
            const float wt  = 0.375f + 0.5f*(float)(ry>>1) - 0.25f*(float)(ry&1);
            const float wtm = wt * NLOG2E, wbm = NLOG2E - wtm;
            f32x2 wtm2; wtm2.x = wtm; wtm2.y = wtm;
            f32x2 wbm2; wbm2.x = wbm; wbm2.y = wbm;
            const int cb = (pp % 288u) >> 2;                 // even

            // taps: colidx cb..cb+3 = real cols cb-1..cb+2; rows y0loc, y0loc+1
            const char* ap = smem + y0loc*Y_STR + qb + 4*cb;
            const uint2 ta = *(const uint2*)(ap);
            const uint2 tb = *(const uint2*)(ap + 8);
            const uint2 ba = *(const uint2*)(ap + Y_STR);
            const uint2 bb = *(const uint2*)(ap + Y_STR + 8);

            f32x2 t0, t1, t2, t3, b0, b1, b2, b3;
            t0.x = blo(ta.x); t0.y = bhi(ta.x);
            t1.x = blo(ta.y); t1.y = bhi(ta.y);
            t2.x = blo(tb.x); t2.y = bhi(tb.x);
            t3.x = blo(tb.y); t3.y = bhi(tb.y);
            b0.x = blo(ba.x); b0.y = bhi(ba.x);
            b1.x = blo(ba.y); b1.y = bhi(ba.y);
            b2.x = blo(bb.x); b2.y = bhi(bb.x);
            b3.x = blo(bb.y); b3.y = bhi(bb.y);

            // row interp (-log2e folded), packed (L,S)
            f32x2 v0 = pk_fma(b0, wbm2, pk_mul(t0, wtm2));
            f32x2 v1 = pk_fma(b1, wbm2, pk_mul(t1, wtm2));
            f32x2 v2 = pk_fma(b2, wbm2, pk_mul(t2, wtm2));
            f32x2 v3 = pk_fma(b3, wbm2, pk_mul(t3, wtm2));

            // col interp: 8 px (validated pattern)
            f32x2 m0 = pk_fma(v1, c625, pk_mul(v0, c375));
            f32x2 m1 = pk_fma(v1, c875, pk_mul(v0, c125));
            f32x2 m2 = pk_fma(v1, c875, pk_mul(v2, c125));
            f32x2 m3 = pk_fma(v1, c625, pk_mul(v2, c375));
            f32x2 m4 = pk_fma(v2, c625, pk_mul(v1, c375));
            f32x2 m5 = pk_fma(v2, c875, pk_mul(v1, c125));
            f32x2 m6 = pk_fma(v2, c875, pk_mul(v3, c125));
            f32x2 m7 = pk_fma(v2, c625, pk_mul(v3, c375));

            f32x2 a0 = sigm2m(m0), a1 = sigm2m(m1), a2 = sigm2m(m2), a3 = sigm2m(m3);
            f32x2 a4 = sigm2m(m4), a5 = sigm2m(m5), a6 = sigm2m(m6), a7 = sigm2m(m7);

            // conditioned IoU (u>0 <=> m<0), packed over px pairs
            f32x2 pl, ps;
            pl.x = (m0.x<0.f)?a0.x:0.f;  pl.y = (m1.x<0.f)?a1.x:0.f;
            ps.x = (m0.y<0.f)?a0.y:0.f;  ps.y = (m1.y<0.f)?a1.y:0.f;
            iN2 = pk_fma(pl, ps, iN2); iD2 = iD2 + pl;
            pl.x = (m2.x<0.f)?a2.x:0.f;  pl.y = (m3.x<0.f)?a3.x:0.f;
            ps.x = (m2.y<0.f)?a2.y:0.f;  ps.y = (m3.y<0.f)?a3.y:0.f;
            iN2 = pk_fma(pl, ps, iN2); iD2 = iD2 + pl;
            pl.x = (m4.x<0.f)?a4.x:0.f;  pl.y = (m5.x<0.f)?a5.x:0.f;
            ps.x = (m4.y<0.f)?a4.y:0.f;  ps.y = (m5.y<0.f)?a5.y:0.f;
            iN2 = pk_fma(pl, ps, iN2); iD2 = iD2 + pl;
            pl.x = (m6.x<0.f)?a6.x:0.f;  pl.y = (m7.x<0.f)?a7.x:0.f;
            ps.x = (m6.y<0.f)?a6.y:0.f;  ps.y = (m7.y<0.f)?a7.y:0.f;
            iN2 = pk_fma(pl, ps, iN2); iD2 = iD2 + pl;

            // A fragments directly in registers
            short8 fAL, fAS;
            {
                unsigned* u = (unsigned*)&fAL;
                u[0]=cvt_pk_bf16(a0.x,a1.x); u[1]=cvt_pk_bf16(a2.x,a3.x);
                u[2]=cvt_pk_bf16(a4.x,a5.x); u[3]=cvt_pk_bf16(a6.x,a7.x);
                unsigned* v = (unsigned*)&fAS;
                v[0]=cvt_pk_bf16(a0.y,a1.y); v[1]=cvt_pk_bf16(a2.y,a3.y);
                v[2]=cvt_pk_bf16(a4.y,a5.y); v[3]=cvt_pk_bf16(a6.y,a7.y);
            }
            if (padQ) { fAL = ones8; fAS = ones8; }   // ones rows -> gS trick

            // B fragment from g tile (wave-private; same-wave order => no barrier)
            const int fo = (arowc*128 + 64*ks + 16*kg) ^ ((arowc&7)<<4);
            short8 fB = *(const short8*)(gpl + fo);
            accL = __builtin_amdgcn_mfma_f32_16x16x32_bf16(fAL, fB, accL, 0, 0, 0);
            accS = __builtin_amdgcn_mfma_f32_16x16x32_bf16(fAS, fB, accS, 0, 0, 0);
        }
    }

    // --- iou reduce across kg groups; lanes 0-15 hold per-q totals ---
    float iN = iN2.x + iN2.y, iD = iD2.x + iD2.y;
    iN += __shfl_xor(iN, 16); iN += __shfl_xor(iN, 32);
    iD += __shfl_xor(iD, 16); iD += __shfl_xor(iD, 32);

    __syncthreads();       // done with pred LDS; cred aliases it now
#pragma unroll
    for (int e = 0; e < 4; e++) { cred[wv][lane][e] = accL[e]; cred[wv][lane][4+e] = accS[e]; }
    if (lane < 16) { iredN[wv*16 + lane] = iN; iredD[wv*16 + lane] = iD; }
    __syncthreads();

    float* wsb = ws + (size_t)blk * PART_F;
    if (threadIdx.x < 64) {
        const int l = threadIdx.x;
        const int colx = l & 15, rb = (l >> 4) * 4;
        if (colx < 9) {
#pragma unroll
            for (int e = 0; e < 4; e++) {
                float sLv = 0.f, sSv = 0.f;
#pragma unroll
                for (int w = 0; w < 8; w++) { sLv += cred[w][l][e]; sSv += cred[w][l][4+e]; }
                wsb[colx*16 + rb + e] = sLv;
                wsb[144 + colx*16 + rb + e] = sSv;
            }
        }
    }
    if (threadIdx.x < 16) {
        float sn = 0.f, sd = 0.f;
#pragma unroll
        for (int w = 0; w < 8; w++) { sn += iredN[w*16 + threadIdx.x]; sd += iredD[w*16 + threadIdx.x]; }
        wsb[288 + threadIdx.x] = sn;
        wsb[304 + threadIdx.x] = sd;
    }
}

// ---------------------------------------------------------------------------
// Kernel 2: reduce NCH chunk partials -> per-(t,qg) sums
// ---------------------------------------------------------------------------
__global__ __launch_bounds__(320) void reduce_kernel(float* __restrict__ ws)
{
    const int tq = blockIdx.x;               // t*NQG + qg
    for (int s = threadIdx.x; s < PART_F; s += 320) {
        float acc = 0.f;
        const float* base = ws + (size_t)tq*NCH*PART_F + s;
#pragma unroll 3
        for (int c = 0; c < NCH; c++) acc += base[(size_t)c*PART_F];
        ws[WS2_OFF + (size_t)tq*PART_F + s] = acc;
    }
}

// ---------------------------------------------------------------------------
// Kernel 3: finalize 800 outputs (gS from qg=6 pad ones-rows, row 4)
// ---------------------------------------------------------------------------
__global__ __launch_bounds__(64) void final_kernel(
    const float* __restrict__ pirL, const float* __restrict__ pirS,
    const int* __restrict__ refidx, const float* __restrict__ ws,
    float* __restrict__ out)
{
    const int gid = blockIdx.x*64 + threadIdx.x;
    if (gid >= P_*N_) return;
    const int p = gid >> 3, n = gid & 7;
    const int b = p / 50, qloc = p % 50;
    const int qg = p >> 4, row = p & 15;
    const int rg0 = refidx[0], rg1 = refidx[1] + 4;   // ref_indices[b] + b*(N/B)
    const bool isref = (n == rg0) || (n == rg1);

    float acc = 0.f;
    for (int t = 0; t < T_; t++) {
        const float* b2 = ws + WS2_OFF + (size_t)(t*NQG + qg)*PART_F;
        const float dL = b2[n*16 + row];
        const float sL = b2[128 + row];          // ones column (col 8)
        const float dS = b2[144 + n*16 + row];
        const float sS = b2[144 + 128 + row];
        const float iN = b2[288 + row];
        const float iD = b2[304 + row];
        // tgt sum from qg=6 pad ones-row (row 4 = first pad query)
        const float gS = ws[WS2_OFF + (size_t)(t*NQG + (NQG-1))*PART_F + n*16 + 4];

        const float diceL = (2.f*dL + 1.f) / (sL + gS + 1.f);
        const float diceS = (2.f*dS + 1.f) / (sS + gS + 1.f);
        const float iou   = (iN + 1.f) / (iD + 1.f);
        const int ib = ((t*2 + b)*50 + qloc)*2;
        const float l0 = pirL[ib], l1 = pirL[ib+1];
        const float m0 = pirS[ib], m1 = pirS[ib+1];
        const float pl = isref ? 1.f/(1.f + __expf(l1 - l0)) : 1.f/(1.f + __expf(l0 - l1));
        const float ps = isref ? 1.f/(1.f + __expf(m1 - m0)) : 1.f/(1.f + __expf(m0 - m1));
        acc += diceL + diceS + iou + pl + ps;
    }
    out[gid] = -acc * (1.0f / (float)T_);
}

extern "C" void kernel_launch(void* const* d_in, const int* in_sizes, int n_in,
                              void* d_out, int out_size, void* d_ws, size_t ws_size,
                              hipStream_t stream) {
    const float* predL = (const float*)d_in[0];   // [6,2,50,72,72]
    const float* predS = (const float*)d_in[1];   // [6,2,50,72,72]
    const float* pirL  = (const float*)d_in[2];   // [6,2,50,2]
    const float* pirS  = (const float*)d_in[3];   // [6,2,50,2]
    const float* tgt   = (const float*)d_in[4];   // [6,8,288,288]
    const int*   refix = (const int*)d_in[5];     // [2]
    float* ws  = (float*)d_ws;                    // ~255,360 floats (~1.0 MB)
    float* out = (float*)d_out;                   // 800 floats

    mfma_partial<<<T_*NQG*NCH, 512, 0, stream>>>(predL, predS, tgt, ws);
    reduce_kernel<<<T_*NQG, 320, 0, stream>>>(ws);
    final_kernel<<<(P_*N_ + 63)/64, 64, 0, stream>>>(pirL, pirS, refix, ws, out);
}

// Round 18
// 58.004 us; speedup vs baseline: 1.2409x; 1.2409x over previous
//
#include <hip/hip_runtime.h>
#include <hip/hip_bf16.h>

// T=6, B=2, Q=50 -> P=100 queries; N=8 targets; 72x72 -> 288x288 bilinear
// (align_corners=False, 4x => fixed weights); out C[B,Q,N] = 800 f32.
// R18 = R17 with __launch_bounds__(512, 4): R17's (512,8) forced a 64-VGPR
// cap -> 51MB scratch spill (WRITE_SIZE counter). Cap 128 removes the spill;
// LDS (39.9KB -> 4 blocks/CU) stays the binding resource.

#define T_      6
#define P_      100
#define N_      8
#define HIN     72
#define SIN     (HIN*HIN)        // 5184
#define HOUT    288
#define S_OUT   (HOUT*HOUT)      // 82944
#define NQG     7                // query groups of 16 (100 -> 112 padded)
#define NCH     18               // 16-output-row slabs per t
#define PART_F  320              // floats per partial slot
#define WS2_OFF (T_*NQG*NCH*PART_F)          // 241920
#define NQUAD   (S_OUT/4)        // 20736 float4 per mask
#define NLOG2E  (-1.4426950408889634f)

// LDS map (bytes):
//  pred u32(L|S) [yloc6][q16][colidx74]  colidx = realcol+1
//    strides: col 4, q 296, yloc 4736 ; total 28416
//  g tiles [wave8][1280] : 28416 .. 38656
//  iredN [8][16] f32 : 38656 ; iredD : 39168 ; total 39680
//  cred [8][64][8] f32 (16KB) aliases pred area post-loop
#define Q_STR   296
#define Y_STR   4736
#define LDS_G   28416
#define GW      1280
#define LDS_IRN (LDS_G + 8*GW)        // 38656
#define LDS_IRD (LDS_IRN + 512)       // 39168
#define LDS_TOT (LDS_IRD + 512)       // 39680

typedef __attribute__((ext_vector_type(8))) short short8;
typedef __attribute__((ext_vector_type(4))) float f32x4;
typedef __attribute__((ext_vector_type(2))) float f32x2;

__device__ __forceinline__ unsigned cvt_pk_bf16(float lo, float hi) {
    unsigned r;
    asm("v_cvt_pk_bf16_f32 %0, %1, %2" : "=v"(r) : "v"(lo), "v"(hi));
    return r;
}
__device__ __forceinline__ f32x2 pk_mul(f32x2 a, f32x2 b) {
    f32x2 d;
    asm("v_pk_mul_f32 %0, %1, %2" : "=v"(d) : "v"(a), "v"(b));
    return d;
}
__device__ __forceinline__ f32x2 pk_fma(f32x2 a, f32x2 b, f32x2 c) {
    f32x2 d;
    asm("v_pk_fma_f32 %0, %1, %2, %3" : "=v"(d) : "v"(a), "v"(b), "v"(c));
    return d;
}
__device__ __forceinline__ float blo(unsigned r) { return __uint_as_float(r << 16); }
__device__ __forceinline__ float bhi(unsigned r) { return __uint_as_float(r & 0xffff0000u); }

// a = sigmoid(u) where m = -log2e*u  =>  a = 1/(1+2^m)   (packed L,S)
__device__ __forceinline__ f32x2 sigm2m(f32x2 m) {
    f32x2 e;
    e.x = __builtin_amdgcn_exp2f(m.x);
    e.y = __builtin_amdgcn_exp2f(m.y);
    f32x2 d = e + 1.0f;
    f32x2 r;
    r.x = __builtin_amdgcn_rcpf(d.x);
    r.y = __builtin_amdgcn_rcpf(d.y);
    return r;
}

// ---------------------------------------------------------------------------
// Kernel 1: staged-LDS packed act + MFMA. grid = T_*NQG*NCH, 512 thr (8 waves).
// ---------------------------------------------------------------------------
__global__ __launch_bounds__(512, 4) void mfma_partial(
    const float* __restrict__ predL, const float* __restrict__ predS,
    const float* __restrict__ tgt, float* __restrict__ ws)
{
    __shared__ __align__(16) char smem[LDS_TOT];
    float (*cred)[64][8] = (float (*)[64][8])smem;   // aliases pred area (post-loop)
    float* iredN = (float*)(smem + LDS_IRN);
    float* iredD = (float*)(smem + LDS_IRD);

    const int blk = blockIdx.x;                 // (t*NQG+qg)*NCH + ch
    const int t   = blk / (NQG*NCH);
    const int rem = blk % (NQG*NCH);
    const int qg  = rem / NCH;
    const int ch  = rem % NCH;

    const int lane = threadIdx.x & 63;
    const int wv   = threadIdx.x >> 6;          // 0..7
    char* gpl = smem + LDS_G + wv*GW;

    const int arow = lane & 15;                 // q row (A) / B-col select
    const int kg   = lane >> 4;                 // k-group
    const int arowc = (arow < 9) ? arow : 9;    // g-tile row (9 = shared zeros)

    const float* __restrict__ pLt = predL + (size_t)t*P_*SIN;
    const float* __restrict__ pSt = predS + (size_t)t*P_*SIN;

    // --- one-time staging: 6 input rows x 16 q, interleaved bf16 (L|S) ---
    {
        const int tid = threadIdx.x;
#pragma unroll
        for (int pass = 0; pass < 4; ++pass) {
            const int idx = pass*512 + tid;
            if (idx < 1728) {                          // 96 jobs x 18 float4
                const int job = (idx*3641) >> 16;      // idx / 18
                const int f4i = idx - job*18;
                const int yloc = job >> 4;             // job / 16 (0..5)
                const int ql = job & 15;
                const int qv = min(qg*16 + ql, P_-1);
                const int grow = min(max(4*ch - 1 + yloc, 0), HIN-1);
                const size_t so = (size_t)qv*SIN + grow*HIN + 4*f4i;
                const float4 vL = *(const float4*)(pLt + so);
                const float4 vS = *(const float4*)(pSt + so);
                char* dp = smem + yloc*Y_STR + ql*Q_STR + 4 + 16*f4i;
                *(unsigned*)(dp)    = cvt_pk_bf16(vL.x, vS.x);
                *(unsigned*)(dp+4)  = cvt_pk_bf16(vL.y, vS.y);
                *(unsigned*)(dp+8)  = cvt_pk_bf16(vL.z, vS.z);
                *(unsigned*)(dp+12) = cvt_pk_bf16(vL.w, vS.w);
            }
        }
        if (tid < 192) {   // clamp cols: colidx 0 (real -1) and 73 (real 72)
            const int job = tid >> 1, edge = tid & 1;
            const int yloc = job >> 4;
            const int ql = job & 15;
            const int qv = min(qg*16 + ql, P_-1);
            const int grow = min(max(4*ch - 1 + yloc, 0), HIN-1);
            const size_t so = (size_t)qv*SIN + grow*HIN + (edge ? HIN-1 : 0);
            *(unsigned*)(smem + yloc*Y_STR + ql*Q_STR + (edge ? 292 : 0))
                = cvt_pk_bf16(pLt[so], pSt[so]);
        }
    }

    // g-stage roles (validated): n = lane>>3, f = lane&7
    const int gn = lane >> 3, gf = lane & 7;
    const float4* __restrict__ tgt4 = (const float4*)tgt + (size_t)t*8*NQUAD;
    const int gq0 = gn*NQUAD + gf;
    const int gwoff = (gn*128 + 8*gf) ^ ((gn&7)<<4);
    if (lane < 16) {   // row 8 = ones column; row 9 = shared zero row
        *(uint2*)(gpl + 1024 + 8*lane) = make_uint2(0x3F803F80u, 0x3F803F80u);
        *(uint2*)(gpl + 1152 + 8*lane) = make_uint2(0u, 0u);
    }

    __syncthreads();   // staged pred visible to all waves

    short8 ones8;
#pragma unroll
    for (int j8 = 0; j8 < 8; j8++) ones8[j8] = (short)0x3F80;
    const bool padQ = (qg == NQG-1) && (arow >= 4);

    const f32x2 c375 = {0.375f, 0.375f}, c625 = {0.625f, 0.625f};
    const f32x2 c125 = {0.125f, 0.125f}, c875 = {0.875f, 0.875f};

    f32x4 accL = {0.f,0.f,0.f,0.f}, accS = {0.f,0.f,0.f,0.f};
    f32x2 iN2 = {0.f,0.f}, iD2 = {0.f,0.f};
    const int qb = arow*Q_STR;

    // --- g software pipeline: prefetch iter 0 ---
    float4 ga, gb;
    {
        const int f4b = (ch*4608 + wv*64) >> 2;
        ga = tgt4[gq0 + f4b];
        gb = tgt4[gq0 + f4b + 8];
    }

    for (int it = 0; it < 9; ++it) {
        const int px0 = ch*4608 + it*512 + wv*64;

        // --- stage current g chunk from regs (bf16, swizzled [n][k]) ---
        {
            uint2 pa, pb;
            pa.x = cvt_pk_bf16(ga.x, ga.y); pa.y = cvt_pk_bf16(ga.z, ga.w);
            pb.x = cvt_pk_bf16(gb.x, gb.y); pb.y = cvt_pk_bf16(gb.z, gb.w);
            *(uint2*)(gpl + gwoff) = pa;
            *(uint2*)(gpl + (gwoff ^ 64)) = pb;   // base bit6==0 pre-swz
        }
        // --- prefetch next iter's g: latency hides under the act stretch ---
        if (it < 8) {
            const int f4b = (px0 + 512) >> 2;
            ga = tgt4[gq0 + f4b];
            gb = tgt4[gq0 + f4b + 8];
        }

#pragma unroll
        for (int ks = 0; ks < 2; ++ks) {
            const unsigned pp = px0 + 32*ks + 8*kg;   // lane's 8-px start
            const unsigned row = pp / 288u;
            const int ry = row & 3, j = row >> 2;
            const int y0loc = (j - 4*ch) + (ry >> 1);        // slab-local top row
            const float wt  = 0.375f + 0.5f*(float)(ry>>1) - 0.25f*(float)(ry&1);
            const float wtm = wt * NLOG2E, wbm = NLOG2E - wtm;
            f32x2 wtm2; wtm2.x = wtm; wtm2.y = wtm;
            f32x2 wbm2; wbm2.x = wbm; wbm2.y = wbm;
            const int cb = (pp % 288u) >> 2;                 // even

            // taps: colidx cb..cb+3 = real cols cb-1..cb+2; rows y0loc, y0loc+1
            const char* ap = smem + y0loc*Y_STR + qb + 4*cb;
            const uint2 ta = *(const uint2*)(ap);
            const uint2 tb = *(const uint2*)(ap + 8);
            const uint2 ba = *(const uint2*)(ap + Y_STR);
            const uint2 bb = *(const uint2*)(ap + Y_STR + 8);

            f32x2 t0, t1, t2, t3, b0, b1, b2, b3;
            t0.x = blo(ta.x); t0.y = bhi(ta.x);
            t1.x = blo(ta.y); t1.y = bhi(ta.y);
            t2.x = blo(tb.x); t2.y = bhi(tb.x);
            t3.x = blo(tb.y); t3.y = bhi(tb.y);
            b0.x = blo(ba.x); b0.y = bhi(ba.x);
            b1.x = blo(ba.y); b1.y = bhi(ba.y);
            b2.x = blo(bb.x); b2.y = bhi(bb.x);
            b3.x = blo(bb.y); b3.y = bhi(bb.y);

            // row interp (-log2e folded), packed (L,S)
            f32x2 v0 = pk_fma(b0, wbm2, pk_mul(t0, wtm2));
            f32x2 v1 = pk_fma(b1, wbm2, pk_mul(t1, wtm2));
            f32x2 v2 = pk_fma(b2, wbm2, pk_mul(t2, wtm2));
            f32x2 v3 = pk_fma(b3, wbm2, pk_mul(t3, wtm2));

            // col interp: 8 px (validated pattern)
            f32x2 m0 = pk_fma(v1, c625, pk_mul(v0, c375));
            f32x2 m1 = pk_fma(v1, c875, pk_mul(v0, c125));
            f32x2 m2 = pk_fma(v1, c875, pk_mul(v2, c125));
            f32x2 m3 = pk_fma(v1, c625, pk_mul(v2, c375));
            f32x2 m4 = pk_fma(v2, c625, pk_mul(v1, c375));
            f32x2 m5 = pk_fma(v2, c875, pk_mul(v1, c125));
            f32x2 m6 = pk_fma(v2, c875, pk_mul(v3, c125));
            f32x2 m7 = pk_fma(v2, c625, pk_mul(v3, c375));

            f32x2 a0 = sigm2m(m0), a1 = sigm2m(m1), a2 = sigm2m(m2), a3 = sigm2m(m3);
            f32x2 a4 = sigm2m(m4), a5 = sigm2m(m5), a6 = sigm2m(m6), a7 = sigm2m(m7);

            // conditioned IoU (u>0 <=> m<0), packed over px pairs
            f32x2 pl, ps;
            pl.x = (m0.x<0.f)?a0.x:0.f;  pl.y = (m1.x<0.f)?a1.x:0.f;
            ps.x = (m0.y<0.f)?a0.y:0.f;  ps.y = (m1.y<0.f)?a1.y:0.f;
            iN2 = pk_fma(pl, ps, iN2); iD2 = iD2 + pl;
            pl.x = (m2.x<0.f)?a2.x:0.f;  pl.y = (m3.x<0.f)?a3.x:0.f;
            ps.x = (m2.y<0.f)?a2.y:0.f;  ps.y = (m3.y<0.f)?a3.y:0.f;
            iN2 = pk_fma(pl, ps, iN2); iD2 = iD2 + pl;
            pl.x = (m4.x<0.f)?a4.x:0.f;  pl.y = (m5.x<0.f)?a5.x:0.f;
            ps.x = (m4.y<0.f)?a4.y:0.f;  ps.y = (m5.y<0.f)?a5.y:0.f;
            iN2 = pk_fma(pl, ps, iN2); iD2 = iD2 + pl;
            pl.x = (m6.x<0.f)?a6.x:0.f;  pl.y = (m7.x<0.f)?a7.x:0.f;
            ps.x = (m6.y<0.f)?a6.y:0.f;  ps.y = (m7.y<0.f)?a7.y:0.f;
            iN2 = pk_fma(pl, ps, iN2); iD2 = iD2 + pl;

            // A fragments directly in registers
            short8 fAL, fAS;
            {
                unsigned* u = (unsigned*)&fAL;
                u[0]=cvt_pk_bf16(a0.x,a1.x); u[1]=cvt_pk_bf16(a2.x,a3.x);
                u[2]=cvt_pk_bf16(a4.x,a5.x); u[3]=cvt_pk_bf16(a6.x,a7.x);
                unsigned* v = (unsigned*)&fAS;
                v[0]=cvt_pk_bf16(a0.y,a1.y); v[1]=cvt_pk_bf16(a2.y,a3.y);
                v[2]=cvt_pk_bf16(a4.y,a5.y); v[3]=cvt_pk_bf16(a6.y,a7.y);
            }
            if (padQ) { fAL = ones8; fAS = ones8; }   // ones rows -> gS trick

            // B fragment from g tile (wave-private; same-wave order => no barrier)
            const int fo = (arowc*128 + 64*ks + 16*kg) ^ ((arowc&7)<<4);
            short8 fB = *(const short8*)(gpl + fo);
            accL = __builtin_amdgcn_mfma_f32_16x16x32_bf16(fAL, fB, accL, 0, 0, 0);
            accS = __builtin_amdgcn_mfma_f32_16x16x32_bf16(fAS, fB, accS, 0, 0, 0);
        }
    }

    // --- iou reduce across kg groups; lanes 0-15 hold per-q totals ---
    float iN = iN2.x + iN2.y, iD = iD2.x + iD2.y;
    iN += __shfl_xor(iN, 16); iN += __shfl_xor(iN, 32);
    iD += __shfl_xor(iD, 16); iD += __shfl_xor(iD, 32);

    __syncthreads();       // done with pred LDS; cred aliases it now
#pragma unroll
    for (int e = 0; e < 4; e++) { cred[wv][lane][e] = accL[e]; cred[wv][lane][4+e] = accS[e]; }
    if (lane < 16) { iredN[wv*16 + lane] = iN; iredD[wv*16 + lane] = iD; }
    __syncthreads();

    float* wsb = ws + (size_t)blk * PART_F;
    if (threadIdx.x < 64) {
        const int l = threadIdx.x;
        const int colx = l & 15, rb = (l >> 4) * 4;
        if (colx < 9) {
#pragma unroll
            for (int e = 0; e < 4; e++) {
                float sLv = 0.f, sSv = 0.f;
#pragma unroll
                for (int w = 0; w < 8; w++) { sLv += cred[w][l][e]; sSv += cred[w][l][4+e]; }
                wsb[colx*16 + rb + e] = sLv;
                wsb[144 + colx*16 + rb + e] = sSv;
            }
        }
    }
    if (threadIdx.x < 16) {
        float sn = 0.f, sd = 0.f;
#pragma unroll
        for (int w = 0; w < 8; w++) { sn += iredN[w*16 + threadIdx.x]; sd += iredD[w*16 + threadIdx.x]; }
        wsb[288 + threadIdx.x] = sn;
        wsb[304 + threadIdx.x] = sd;
    }
}

// ---------------------------------------------------------------------------
// Kernel 2: reduce NCH chunk partials -> per-(t,qg) sums
// ---------------------------------------------------------------------------
__global__ __launch_bounds__(320) void reduce_kernel(float* __restrict__ ws)
{
    const int tq = blockIdx.x;               // t*NQG + qg
    for (int s = threadIdx.x; s < PART_F; s += 320) {
        float acc = 0.f;
        const float* base = ws + (size_t)tq*NCH*PART_F + s;
#pragma unroll 3
        for (int c = 0; c < NCH; c++) acc += base[(size_t)c*PART_F];
        ws[WS2_OFF + (size_t)tq*PART_F + s] = acc;
    }
}

// ---------------------------------------------------------------------------
// Kernel 3: finalize 800 outputs (gS from qg=6 pad ones-rows, row 4)
// ---------------------------------------------------------------------------
__global__ __launch_bounds__(64) void final_kernel(
    const float* __restrict__ pirL, const float* __restrict__ pirS,
    const int* __restrict__ refidx, const float* __restrict__ ws,
    float* __restrict__ out)
{
    const int gid = blockIdx.x*64 + threadIdx.x;
    if (gid >= P_*N_) return;
    const int p = gid >> 3, n = gid & 7;
    const int b = p / 50, qloc = p % 50;
    const int qg = p >> 4, row = p & 15;
    const int rg0 = refidx[0], rg1 = refidx[1] + 4;   // ref_indices[b] + b*(N/B)
    const bool isref = (n == rg0) || (n == rg1);

    float acc = 0.f;
    for (int t = 0; t < T_; t++) {
        const float* b2 = ws + WS2_OFF + (size_t)(t*NQG + qg)*PART_F;
        const float dL = b2[n*16 + row];
        const float sL = b2[128 + row];          // ones column (col 8)
        const float dS = b2[144 + n*16 + row];
        const float sS = b2[144 + 128 + row];
        const float iN = b2[288 + row];
        const float iD = b2[304 + row];
        // tgt sum from qg=6 pad ones-row (row 4 = first pad query)
        const float gS = ws[WS2_OFF + (size_t)(t*NQG + (NQG-1))*PART_F + n*16 + 4];

        const float diceL = (2.f*dL + 1.f) / (sL + gS + 1.f);
        const float diceS = (2.f*dS + 1.f) / (sS + gS + 1.f);
        const float iou   = (iN + 1.f) / (iD + 1.f);
        const int ib = ((t*2 + b)*50 + qloc)*2;
        const float l0 = pirL[ib], l1 = pirL[ib+1];
        const float m0 = pirS[ib], m1 = pirS[ib+1];
        const float pl = isref ? 1.f/(1.f + __expf(l1 - l0)) : 1.f/(1.f + __expf(l0 - l1));
        const float ps = isref ? 1.f/(1.f + __expf(m1 - m0)) : 1.f/(1.f + __expf(m0 - m1));
        acc += diceL + diceS + iou + pl + ps;
    }
    out[gid] = -acc * (1.0f / (float)T_);
}

extern "C" void kernel_launch(void* const* d_in, const int* in_sizes, int n_in,
                              void* d_out, int out_size, void* d_ws, size_t ws_size,
                              hipStream_t stream) {
    const float* predL = (const float*)d_in[0];   // [6,2,50,72,72]
    const float* predS = (const float*)d_in[1];   // [6,2,50,72,72]
    const float* pirL  = (const float*)d_in[2];   // [6,2,50,2]
    const float* pirS  = (const float*)d_in[3];   // [6,2,50,2]
    const float* tgt   = (const float*)d_in[4];   // [6,8,288,288]
    const int*   refix = (const int*)d_in[5];     // [2]
    float* ws  = (float*)d_ws;                    // ~255,360 floats (~1.0 MB)
    float* out = (float*)d_out;                   // 800 floats

    mfma_partial<<<T_*NQG*NCH, 512, 0, stream>>>(predL, predS, tgt, ws);
    reduce_kernel<<<T_*NQG, 320, 0, stream>>>(ws);
    final_kernel<<<(P_*N_ + 63)/64, 64, 0, stream>>>(pirL, pirS, refix, ws, out);
}